// Round 16
// baseline (1161.178 us; speedup 1.0000x reference)
//
#include <hip/hip_runtime.h>

#define DD 2048
#define SEQ 2048
#define NH 16
#define NKV 4
#define HD 128
#define FFD 5632
#define NL 2

typedef __bf16 bf16x8 __attribute__((ext_vector_type(8)));
typedef float f32x4 __attribute__((ext_vector_type(4)));

#define AS1 __attribute__((address_space(1)))
#define AS3 __attribute__((address_space(3)))

__device__ __forceinline__ unsigned short f2bf(float f) {
    unsigned int u = __builtin_bit_cast(unsigned int, f);
    u += 0x7fffu + ((u >> 16) & 1u);   // round-to-nearest-even
    return (unsigned short)(u >> 16);
}

// ---------------- shared transpose tile body (64x64) ----------------
__device__ __forceinline__ void tc_body(float (*tile)[65],
                                        const float* __restrict__ src,
                                        unsigned short* __restrict__ dst,
                                        int ld_src, int ld_dst, int bx, int by, int nmap)
{
    int c0 = bx * 64, r0 = by * 64;
    int tx = threadIdx.x & 15, ty = threadIdx.x >> 4;
#pragma unroll
    for (int i = 0; i < 4; ++i) {
        int r = ty + i * 16;
        float4 v = *(const float4*)(src + (size_t)(r0 + r) * ld_src + c0 + tx * 4);
        tile[r][tx * 4 + 0] = v.x; tile[r][tx * 4 + 1] = v.y;
        tile[r][tx * 4 + 2] = v.z; tile[r][tx * 4 + 3] = v.w;
    }
    __syncthreads();
#pragma unroll
    for (int i = 0; i < 4; ++i) {
        int c = ty + i * 16;
        int cc = c0 + c;
        int dr = cc;
        if (nmap == 1) dr = ((cc >> 4) << 5) | (cc & 15);
        else if (nmap == 2) dr = (((cc >> 4) << 5) | (cc & 15)) + 16;
        ushort4 o;
        o.x = f2bf(tile[tx * 4 + 0][c]); o.y = f2bf(tile[tx * 4 + 1][c]);
        o.z = f2bf(tile[tx * 4 + 2][c]); o.w = f2bf(tile[tx * 4 + 3][c]);
        *(ushort4*)(dst + (size_t)dr * ld_dst + r0 + tx * 4) = o;
    }
}

// ---------------- fused prep: all weight transposes + embedding gather ----------
__global__ __launch_bounds__(256)
void prep_all(const float* __restrict__ wqkv, const float* __restrict__ wo,
              const float* __restrict__ w1, const float* __restrict__ w3,
              const float* __restrict__ w2, const float* __restrict__ wh,
              const int* __restrict__ ids, const float* __restrict__ wemb,
              unsigned short* __restrict__ WQKVT, unsigned short* __restrict__ WOT,
              unsigned short* __restrict__ W13T, unsigned short* __restrict__ W2T,
              unsigned short* __restrict__ WHT, float* __restrict__ X)
{
    __shared__ float tile[64][65];
    int bid = (int)blockIdx.x;
    if (bid < 16000) {
        tc_body(tile, wh, WHT, 32000, 2048, bid % 500, bid / 500, 0);
    } else if (bid < 21632) {
        int local = bid - 16000;
        int z = local / 2816, r = local % 2816;
        tc_body(tile, w1 + (size_t)z * 2048 * 5632, W13T + (size_t)z * 11264 * 2048,
                5632, 2048, r % 88, r / 88, 1);
    } else if (bid < 27264) {
        int local = bid - 21632;
        int z = local / 2816, r = local % 2816;
        tc_body(tile, w3 + (size_t)z * 2048 * 5632, W13T + (size_t)z * 11264 * 2048,
                5632, 2048, r % 88, r / 88, 2);
    } else if (bid < 32896) {
        int local = bid - 27264;
        int z = local / 2816, r = local % 2816;
        tc_body(tile, w2 + (size_t)z * 5632 * 2048, W2T + (size_t)z * 2048 * 5632,
                2048, 5632, r % 32, r / 32, 0);
    } else if (bid < 35968) {
        int local = bid - 32896;
        int z = local / 1536, r = local % 1536;
        tc_body(tile, wqkv + (size_t)z * 2048 * 3072, WQKVT + (size_t)z * 3072 * 2048,
                3072, 2048, r % 48, r / 48, 0);
    } else if (bid < 38016) {
        int local = bid - 35968;
        int z = local / 1024, r = local % 1024;
        tc_body(tile, wo + (size_t)z * 2048 * 2048, WOT + (size_t)z * 2048 * 2048,
                2048, 2048, r % 32, r / 32, 0);
    } else {
        int s = bid - 38016;
        int id = ids[s];
        const float4* src = (const float4*)(wemb + (size_t)id * DD);
        float4* dst = (float4*)(X + (size_t)s * DD);
        dst[threadIdx.x] = src[threadIdx.x];
        dst[threadIdx.x + 256] = src[threadIdx.x + 256];
    }
}

// ---------------- fused RMSNorm -> bf16 ----------------
__global__ __launch_bounds__(256)
void rmsnorm_bf16(const float* __restrict__ x, const float* __restrict__ w,
                  unsigned short* __restrict__ out)
{
    int row = blockIdx.x;
    int t = threadIdx.x;
    const float4* xr = (const float4*)(x + (size_t)row * DD);
    float4 v0 = xr[t], v1 = xr[t + 256];
    float ss = v0.x * v0.x + v0.y * v0.y + v0.z * v0.z + v0.w * v0.w
             + v1.x * v1.x + v1.y * v1.y + v1.z * v1.z + v1.w * v1.w;
#pragma unroll
    for (int off = 32; off; off >>= 1) ss += __shfl_down(ss, off);
    __shared__ float red[4];
    if ((t & 63) == 0) red[t >> 6] = ss;
    __syncthreads();
    float sc = rsqrtf((red[0] + red[1] + red[2] + red[3]) * (1.0f / DD) + 1e-5f);
    const float4* wr = (const float4*)w;
    float4 w0 = wr[t], w1v = wr[t + 256];
    ushort4 o0, o1;
    o0.x = f2bf(v0.x * sc * w0.x);  o0.y = f2bf(v0.y * sc * w0.y);
    o0.z = f2bf(v0.z * sc * w0.z);  o0.w = f2bf(v0.w * sc * w0.w);
    o1.x = f2bf(v1.x * sc * w1v.x); o1.y = f2bf(v1.y * sc * w1v.y);
    o1.z = f2bf(v1.z * sc * w1v.z); o1.w = f2bf(v1.w * sc * w1v.w);
    ushort4* op = (ushort4*)(out + (size_t)row * DD);
    op[t] = o0;
    op[t + 256] = o1;
}

// ---------------- bf16 MFMA GEMM (128x128 tile, 2-phase counted-vmcnt) ----------
// MODE 0: C[M,N] fp32 (+ optional residual).
// MODE 1: QKV epilogue — RoPE(q,k) head-major bf16 to Qb/Kb; V transposed to VT.
template<int MODE>
__global__ __launch_bounds__(256)
void gemm_bf16(const unsigned short* __restrict__ A, const unsigned short* __restrict__ B,
               float* __restrict__ C, const float* __restrict__ Res,
               unsigned short* __restrict__ Qb, unsigned short* __restrict__ Kb,
               unsigned short* __restrict__ VTp, const float* __restrict__ fcp,
               int N, int K, int mT)
{
    __shared__ __attribute__((aligned(16))) unsigned char smem[65536];
    const int tid = threadIdx.x;
    const int lane = tid & 63;
    const int w = tid >> 6;
    const int nwg = gridDim.x;          // multiple of 8 (launcher guarantees)
    const int qq = nwg >> 3;
    const int logical = ((int)blockIdx.x & 7) * qq + ((int)blockIdx.x >> 3);
    const int m0 = (logical % mT) * 128;
    const int n0 = (logical / mT) * 128;
    const int wm = (w >> 1) * 64, wn = (w & 1) * 64;
    const int lrow = lane & 15, lgrp = lane >> 4;
    const int NT = K >> 6;

    f32x4 acc[4][4];
#pragma unroll
    for (int i = 0; i < 4; ++i)
#pragma unroll
        for (int j = 0; j < 4; ++j) acc[i][j] = 0.f;

    auto stage = [&](int bsel, int kt) {
#pragma unroll
        for (int it = 0; it < 4; ++it) {
            int o = it * 4096 + tid * 16;              // linear LDS byte offset
            int row = o >> 7;
            int col = (o & 127) ^ ((row & 7) << 4);    // pre-swizzled source column
            const char* ga = (const char*)A + ((size_t)(m0 + row) * K + kt) * 2 + col;
            const char* gb = (const char*)B + ((size_t)(n0 + row) * K + kt) * 2 + col;
            __builtin_amdgcn_global_load_lds(
                (AS1 const void*)ga,
                (AS3 void*)(smem + bsel * 32768 + it * 4096 + w * 1024),
                16, 0, 0);
            __builtin_amdgcn_global_load_lds(
                (AS1 const void*)gb,
                (AS3 void*)(smem + bsel * 32768 + 16384 + it * 4096 + w * 1024),
                16, 0, 0);
        }
    };

    stage(0, 0);
    int cur = 0;
    for (int t = 0; t < NT; ++t) {
        if (t + 1 < NT) {
            stage(cur ^ 1, (t + 1) << 6);
            asm volatile("s_waitcnt vmcnt(8)" ::: "memory");   // tile t landed; t+1 in flight
        } else {
            asm volatile("s_waitcnt vmcnt(0)" ::: "memory");   // last tile: nothing newer
        }
        __builtin_amdgcn_s_barrier();
        __builtin_amdgcn_sched_barrier(0);
        const unsigned char* buf = smem + cur * 32768;
#pragma unroll
        for (int kk = 0; kk < 2; ++kk) {
            bf16x8 af[4], bfr[4];
            int cb = kk * 64 + lgrp * 16;
#pragma unroll
            for (int i = 0; i < 4; ++i) {
                int ra = wm + i * 16 + lrow;
                af[i] = *(const bf16x8*)(buf + ra * 128 + (cb ^ ((ra & 7) << 4)));
                int rb = wn + i * 16 + lrow;
                bfr[i] = *(const bf16x8*)(buf + 16384 + rb * 128 + (cb ^ ((rb & 7) << 4)));
            }
#pragma unroll
            for (int i = 0; i < 4; ++i)
#pragma unroll
                for (int j = 0; j < 4; ++j)
                    acc[i][j] = __builtin_amdgcn_mfma_f32_16x16x32_bf16(af[i], bfr[j], acc[i][j], 0, 0, 0);
        }
        __builtin_amdgcn_s_barrier();
        cur ^= 1;
    }

    if constexpr (MODE == 0) {
        const bool hasRes = (Res != nullptr);
#pragma unroll
        for (int i = 0; i < 4; ++i)
#pragma unroll
            for (int j = 0; j < 4; ++j) {
                int r = m0 + wm + i * 16 + lgrp * 4;
                int c = n0 + wn + j * 16 + lrow;
#pragma unroll
                for (int jj = 0; jj < 4; ++jj) {
                    size_t idx = (size_t)(r + jj) * N + c;
                    float v = acc[i][j][jj];
                    if (hasRes) v += Res[idx];
                    C[idx] = v;
                }
            }
    } else {
        // QKV fused epilogue: cols [0,2048) Q-rope, [2048,2560) K-rope, [2560,3072) V->VT
        const float QSCL = 0.12751741530217758f;  // (1/sqrt(128)) * log2(e)
#pragma unroll
        for (int i = 0; i < 4; ++i)
#pragma unroll
            for (int j = 0; j < 4; ++j) {
                int r = m0 + wm + i * 16 + lgrp * 4;
                int cu = n0 + wn + j * 16;          // wave-uniform
                int d = (cu & 127) + lrow;          // 0..127
                if (cu < 2560) {
                    unsigned short* dst;
                    float scl;
                    if (cu < 2048) { dst = Qb + (size_t)(cu >> 7) * SEQ * HD; scl = QSCL; }
                    else           { dst = Kb + (size_t)((cu - 2048) >> 7) * SEQ * HD; scl = 1.f; }
                    int ip = d >> 1;
                    float sgn = (d & 1) ? 1.f : -1.f;
#pragma unroll
                    for (int jj = 0; jj < 4; ++jj) {
                        int s = r + jj;
                        float own = acc[i][j][jj];
                        float par = __shfl_xor(own, 1);
                        float2 cs = *(const float2*)(fcp + ((size_t)s * 64 + ip) * 2);
                        float o = (own * cs.x + sgn * par * cs.y) * scl;
                        dst[(size_t)s * HD + d] = f2bf(o);
                    }
                } else {
                    int kvh = (cu - 2560) >> 7;
                    ushort4 o4;
                    o4.x = f2bf(acc[i][j][0]); o4.y = f2bf(acc[i][j][1]);
                    o4.z = f2bf(acc[i][j][2]); o4.w = f2bf(acc[i][j][3]);
                    *(ushort4*)(VTp + (size_t)(kvh * 128 + d) * SEQ + r) = o4;
                }
            }
    }
}

// ---------------- bf16 MFMA GEMM: 128x256 tile, 4 waves, BK=32 dbuf --------------
// 2 blocks/CU (LDS 48KB, ~200 VGPR) -> inter-block overlap like the 128^2 kernel,
// with 87 FLOP/B intensity. Row-pair LDS layout + XOR swizzle (R7-verified, 0 bank
// conflicts); 2-phase counted vmcnt(6) (= next tile's 6 loads). Per tile: 12
// ds_read_b128, 32 MFMA. FUSE=0: fp32 C. FUSE=1: W13 silu epilogue -> bf16 G.
template<int FUSE>
__global__ __launch_bounds__(256, 2)
void gemm_bf16_128x256(const unsigned short* __restrict__ A, const unsigned short* __restrict__ B,
                       void* __restrict__ Cout, int N, int K, int mT)
{
    __shared__ __attribute__((aligned(16))) unsigned char smem[49152];
    const int tid = threadIdx.x;
    const int lane = tid & 63;
    const int w = tid >> 6;             // 0..3
    const int nwg = gridDim.x;          // multiple of 8
    const int qq = nwg >> 3;
    const int logical = ((int)blockIdx.x & 7) * qq + ((int)blockIdx.x >> 3);
    const int m0 = (logical % mT) * 128;
    const int n0 = (logical / mT) * 256;
    const int lrow = lane & 15, lgrp = (lane >> 4) & 3;
    const int NT = K >> 5;              // BK=32 tiles

    f32x4 acc[8][4];
#pragma unroll
    for (int i = 0; i < 8; ++i)
#pragma unroll
        for (int j = 0; j < 4; ++j) acc[i][j] = 0.f;

    // swizzled read address pieces (row-pair layout, R7-verified)
    const int X = (((lrow & 1) << 6) | (lgrp << 4)) ^ ((lrow >> 1) << 4);
    const int aoff = (lrow >> 1) * 128 + X;                            // + mi*1024
    const int boff = 8192 + ((w & 3) * 32 + (lrow >> 1)) * 128 + X;    // + nj*1024

    // stage K-tile kt into buffer bsel: A 2 loads (8KB), B 4 loads (16KB)
    auto stage = [&](int bsel, int ktile) {
        const int ktb = ktile << 6;     // byte offset along K (32 elems * 2B)
#pragma unroll
        for (int j = 0; j < 2; ++j) {   // A
            int o = j * 4096 + tid * 16;
            int p = o >> 7;
            int sl = (o & 127) ^ ((p & 7) << 4);
            int r = 2 * p + (sl >> 6);
            int cb = sl & 63;
            const char* g = (const char*)A + (size_t)(m0 + r) * K * 2 + ktb + cb;
            __builtin_amdgcn_global_load_lds(
                (AS1 const void*)g,
                (AS3 void*)(smem + bsel * 24576 + o),
                16, 0, 0);
        }
#pragma unroll
        for (int j = 0; j < 4; ++j) {   // B
            int o = j * 4096 + tid * 16;
            int p = o >> 7;
            int sl = (o & 127) ^ ((p & 7) << 4);
            int r = 2 * p + (sl >> 6);
            int cb = sl & 63;
            const char* g = (const char*)B + (size_t)(n0 + r) * K * 2 + ktb + cb;
            __builtin_amdgcn_global_load_lds(
                (AS1 const void*)g,
                (AS3 void*)(smem + bsel * 24576 + 8192 + o),
                16, 0, 0);
        }
    };

    stage(0, 0);
    int cur = 0;
    for (int t = 0; t < NT; ++t) {
        if (t + 1 < NT) {
            stage(cur ^ 1, t + 1);
            asm volatile("s_waitcnt vmcnt(6)" ::: "memory");   // tile t resident; t+1 in flight
        } else {
            asm volatile("s_waitcnt vmcnt(0)" ::: "memory");
        }
        __builtin_amdgcn_s_barrier();
        __builtin_amdgcn_sched_barrier(0);
        const unsigned char* buf = smem + cur * 24576;
        bf16x8 af[8], bfr[4];
#pragma unroll
        for (int nj = 0; nj < 4; ++nj) bfr[nj] = *(const bf16x8*)(buf + boff + nj * 1024);
#pragma unroll
        for (int mi = 0; mi < 8; ++mi) af[mi] = *(const bf16x8*)(buf + aoff + mi * 1024);
        __builtin_amdgcn_s_setprio(1);
#pragma unroll
        for (int mi = 0; mi < 8; ++mi)
#pragma unroll
            for (int nj = 0; nj < 4; ++nj)
                acc[mi][nj] = __builtin_amdgcn_mfma_f32_16x16x32_bf16(af[mi], bfr[nj], acc[mi][nj], 0, 0, 0);
        __builtin_amdgcn_s_setprio(0);
        __builtin_amdgcn_s_barrier();
        cur ^= 1;
    }

    if constexpr (FUSE == 0) {
        float* C = (float*)Cout;
#pragma unroll
        for (int mi = 0; mi < 8; ++mi)
#pragma unroll
            for (int nj = 0; nj < 4; ++nj) {
                int r = m0 + mi * 16 + lgrp * 4;
                int c = n0 + (w & 3) * 64 + nj * 16 + lrow;
#pragma unroll
                for (int jj = 0; jj < 4; ++jj)
                    C[(size_t)(r + jj) * N + c] = acc[mi][nj][jj];
            }
    } else {
        unsigned short* G = (unsigned short*)Cout;
        const int nbase = n0 + (w & 3) * 64;
#pragma unroll
        for (int mi = 0; mi < 8; ++mi)
#pragma unroll
            for (int p = 0; p < 2; ++p) {
                int r = m0 + mi * 16 + lgrp * 4;
                int cc = (nbase >> 1) + p * 16 + lrow;
#pragma unroll
                for (int jj = 0; jj < 4; ++jj) {
                    float h1 = acc[mi][2 * p][jj];
                    float h3 = acc[mi][2 * p + 1][jj];
                    float g = h1 / (1.f + __expf(-h1)) * h3;
                    G[(size_t)(r + jj) * FFD + cc] = f2bf(g);
                }
            }
    }
}

// ---------------- bf16 MFMA GEMM: 256x256 tile (R7; kept for fallback) -----------
template<int FUSE>
__global__ __launch_bounds__(512, 1)
void gemm_bf16_256(const unsigned short* __restrict__ A, const unsigned short* __restrict__ B,
                   void* __restrict__ Cout, int N, int K, int mT)
{
    __shared__ __attribute__((aligned(16))) unsigned char smem[131072];
    const int tid = threadIdx.x;
    const int lane = tid & 63;
    const int w = tid >> 6;
    const int nwg = gridDim.x;
    const int qq = nwg >> 3;
    const int logical = ((int)blockIdx.x & 7) * qq + ((int)blockIdx.x >> 3);
    const int m0 = (logical % mT) * 256;
    const int n0 = (logical / mT) * 256;
    const int wm2 = (w >> 2) * 128;
    const int lrow = lane & 15, lgrp = (lane >> 4) & 3;
    const int NT = K >> 5;

    f32x4 acc[8][4];
#pragma unroll
    for (int i = 0; i < 8; ++i)
#pragma unroll
        for (int j = 0; j < 4; ++j) acc[i][j] = 0.f;

    const int X = (((lrow & 1) << 6) | (lgrp << 4)) ^ ((lrow >> 1) << 4);
    const int aoff = ((wm2 >> 1) + (lrow >> 1)) * 128 + X;
    const int boff = 16384 + (((w & 3) * 32) + (lrow >> 1)) * 128 + X;

    auto stage_part = [&](int ktile, int part) {
        const unsigned short* base = part ? B : A;
        const int r0 = part ? n0 : m0;
        const int ktb = ktile << 6;
#pragma unroll
        for (int j = 0; j < 2; ++j) {
            int o = j * 8192 + tid * 16;
            int p = o >> 7;
            int sl = (o & 127) ^ ((p & 7) << 4);
            int r = 2 * p + (sl >> 6);
            int cb = sl & 63;
            const char* g = (const char*)base + (size_t)(r0 + r) * K * 2 + ktb + cb;
            __builtin_amdgcn_global_load_lds(
                (AS1 const void*)g,
                (AS3 void*)(smem + (ktile & 3) * 32768 + part * 16384 + o),
                16, 0, 0);
        }
    };

    bf16x8 bE[4], aE[4], bO[4], aO[4], a47[4];

    auto read_ba = [&](int t, bf16x8* bs, bf16x8* as) {
        const unsigned char* buf = smem + (t & 3) * 32768;
#pragma unroll
        for (int nj = 0; nj < 4; ++nj) bs[nj] = *(const bf16x8*)(buf + boff + nj * 1024);
#pragma unroll
        for (int mi = 0; mi < 4; ++mi) as[mi] = *(const bf16x8*)(buf + aoff + mi * 1024);
    };

    auto tile = [&](int t, bf16x8* bc, bf16x8* ac, bf16x8* bn, bf16x8* an) {
        const unsigned char* buf = smem + (t & 3) * 32768;
        if (t + 3 < NT) stage_part(t + 3, 0);
#pragma unroll
        for (int mi = 0; mi < 4; ++mi) a47[mi] = *(const bf16x8*)(buf + aoff + (mi + 4) * 1024);
        asm volatile("s_waitcnt lgkmcnt(4)" ::: "memory");
        __builtin_amdgcn_sched_barrier(0);
        __builtin_amdgcn_s_setprio(1);
#pragma unroll
        for (int mi = 0; mi < 4; ++mi)
#pragma unroll
            for (int nj = 0; nj < 4; ++nj)
                acc[mi][nj] = __builtin_amdgcn_mfma_f32_16x16x32_bf16(ac[mi], bc[nj], acc[mi][nj], 0, 0, 0);
        __builtin_amdgcn_s_setprio(0);
        if (t + 3 < NT) stage_part(t + 3, 1);
        if (t + 1 < NT) {
            if (t + 3 < NT)      { asm volatile("s_waitcnt vmcnt(8)" ::: "memory"); }
            else if (t + 2 < NT) { asm volatile("s_waitcnt vmcnt(4)" ::: "memory"); }
            else                 { asm volatile("s_waitcnt vmcnt(0)" ::: "memory"); }
            __builtin_amdgcn_s_barrier();
            __builtin_amdgcn_sched_barrier(0);
            read_ba(t + 1, bn, an);
            asm volatile("s_waitcnt lgkmcnt(8)" ::: "memory");
        } else {
            asm volatile("s_waitcnt lgkmcnt(0)" ::: "memory");
        }
        __builtin_amdgcn_sched_barrier(0);
        __builtin_amdgcn_s_setprio(1);
#pragma unroll
        for (int mi = 0; mi < 4; ++mi)
#pragma unroll
            for (int nj = 0; nj < 4; ++nj)
                acc[mi + 4][nj] = __builtin_amdgcn_mfma_f32_16x16x32_bf16(a47[mi], bc[nj], acc[mi + 4][nj], 0, 0, 0);
        __builtin_amdgcn_s_setprio(0);
    };

#pragma unroll
    for (int p0 = 0; p0 < 3; ++p0) { stage_part(p0, 0); stage_part(p0, 1); }
    asm volatile("s_waitcnt vmcnt(8)" ::: "memory");
    __builtin_amdgcn_s_barrier();
    __builtin_amdgcn_sched_barrier(0);
    read_ba(0, bE, aE);

    for (int tt = 0; tt < NT; tt += 2) {
        tile(tt, bE, aE, bO, aO);
        tile(tt + 1, bO, aO, bE, aE);
    }

    if constexpr (FUSE == 0) {
        float* C = (float*)Cout;
#pragma unroll
        for (int mi = 0; mi < 8; ++mi)
#pragma unroll
            for (int nj = 0; nj < 4; ++nj) {
                int r = m0 + wm2 + mi * 16 + lgrp * 4;
                int c = n0 + (w & 3) * 64 + nj * 16 + lrow;
#pragma unroll
                for (int jj = 0; jj < 4; ++jj)
                    C[(size_t)(r + jj) * N + c] = acc[mi][nj][jj];
            }
    } else {
        unsigned short* G = (unsigned short*)Cout;
        const int nbase = n0 + (w & 3) * 64;
#pragma unroll
        for (int mi = 0; mi < 8; ++mi)
#pragma unroll
            for (int p = 0; p < 2; ++p) {
                int r = m0 + wm2 + mi * 16 + lgrp * 4;
                int cc = (nbase >> 1) + p * 16 + lrow;
#pragma unroll
                for (int jj = 0; jj < 4; ++jj) {
                    float h1 = acc[mi][2 * p][jj];
                    float h3 = acc[mi][2 * p + 1][jj];
                    float g = h1 / (1.f + __expf(-h1)) * h3;
                    G[(size_t)(r + jj) * FFD + cc] = f2bf(g);
                }
            }
    }
}

// ---------------- flash attention (causal, GQA, exp2-domain, defer-max) ----------
__global__ __launch_bounds__(256)
void attn_fwd(const unsigned short* __restrict__ Qb, const unsigned short* __restrict__ Kb,
              const unsigned short* __restrict__ VTb, unsigned short* __restrict__ O)
{
    __shared__ __attribute__((aligned(16))) unsigned char smem[73728];
    const int bid = (int)blockIdx.x;       // 0..511
    const int j0 = bid & 255;
    const int h = j0 & 15;
    const int qbase = j0 >> 4;             // 0..15
    const int qb = (bid >> 8) ? (31 - qbase) : qbase;
    const int kvh = h >> 2;
    const int tid = threadIdx.x, lane = tid & 63, w = tid >> 6;
    const int lrow = lane & 15, lgrp = lane >> 4;
    const int q0 = qb * 64 + w * 16;
    const float NEG = -1.0e30f;

    bf16x8 qf[4];
    const unsigned short* qrow = Qb + ((size_t)h * SEQ + q0 + lrow) * HD;
#pragma unroll
    for (int c = 0; c < 4; ++c)
        qf[c] = *(const bf16x8*)(qrow + c * 32 + lgrp * 8);

    float m[4], l[4];
    f32x4 oacc[8];
#pragma unroll
    for (int j = 0; j < 8; ++j) oacc[j] = 0.f;
#pragma unroll
    for (int j = 0; j < 4; ++j) { m[j] = NEG; l[j] = 0.f; }

    const char* kbase = (const char*)(Kb + (size_t)kvh * SEQ * HD);
    const char* vbase = (const char*)(VTb + (size_t)kvh * HD * SEQ);
    unsigned char* Pl = smem + 65536 + w * 2048;

    auto stage_kv = [&](int bsel, int t) {
#pragma unroll
        for (int it = 0; it < 4; ++it) {           // K: 16 KB
            int o = it * 4096 + tid * 16;
            int row = o >> 8, col = o & 255;       // 256B rows
            int scol = col ^ ((row & 7) << 4);
            const char* g = kbase + (size_t)(t * 64 + row) * 256 + scol;
            __builtin_amdgcn_global_load_lds(
                (AS1 const void*)g,
                (AS3 void*)(smem + bsel * 32768 + it * 4096 + w * 1024),
                16, 0, 0);
        }
#pragma unroll
        for (int it = 0; it < 4; ++it) {           // VT: 16 KB
            int o = it * 4096 + tid * 16;
            int row = o >> 7, col = o & 127;       // 128B rows
            int scol = col ^ ((row & 7) << 4);
            const char* g = vbase + (size_t)row * (SEQ * 2) + (size_t)t * 128 + scol;
            __builtin_amdgcn_global_load_lds(
                (AS1 const void*)g,
                (AS3 void*)(smem + bsel * 32768 + 16384 + it * 4096 + w * 1024),
                16, 0, 0);
        }
    };

    stage_kv(0, 0);
    int cur = 0;
    for (int t = 0; t <= qb; ++t) {
        if (t < qb) {
            stage_kv(cur ^ 1, t + 1);
            asm volatile("s_waitcnt vmcnt(8)" ::: "memory");   // tile t resident
        } else {
            asm volatile("s_waitcnt vmcnt(0)" ::: "memory");
        }
        __builtin_amdgcn_s_barrier();
        __builtin_amdgcn_sched_barrier(0);
        const unsigned char* kb = smem + cur * 32768;
        const unsigned char* vtb = kb + 16384;

        // S = Q K^T (already in log2 domain via pre-scaled Q)
        f32x4 sf[4];
#pragma unroll
        for (int kf = 0; kf < 4; ++kf) sf[kf] = 0.f;
#pragma unroll
        for (int kf = 0; kf < 4; ++kf) {
            int rb = kf * 16 + lrow;
            int rbase = rb * 256;
            int sw = (rb & 7) << 4;
#pragma unroll
            for (int c = 0; c < 4; ++c) {
                bf16x8 kfr = *(const bf16x8*)(kb + rbase + ((c * 64 + lgrp * 16) ^ sw));
                sf[kf] = __builtin_amdgcn_mfma_f32_16x16x32_bf16(qf[c], kfr, sf[kf], 0, 0, 0);
            }
        }
        const bool diag = (t == qb);
        float mx[4] = {NEG, NEG, NEG, NEG};
#pragma unroll
        for (int kf = 0; kf < 4; ++kf)
#pragma unroll
            for (int j = 0; j < 4; ++j) {
                float v = sf[kf][j];
                if (diag && (t * 64 + kf * 16 + lrow) > (q0 + lgrp * 4 + j)) v = NEG;
                sf[kf][j] = v;
                mx[j] = fmaxf(mx[j], v);
            }
#pragma unroll
        for (int off = 1; off < 16; off <<= 1)
#pragma unroll
            for (int j = 0; j < 4; ++j) mx[j] = fmaxf(mx[j], __shfl_xor(mx[j], off));
        bool need = (mx[0] > m[0] + 8.f) || (mx[1] > m[1] + 8.f) ||
                    (mx[2] > m[2] + 8.f) || (mx[3] > m[3] + 8.f);
        if (__any(need)) {
#pragma unroll
            for (int j = 0; j < 4; ++j) {
                float mn = fmaxf(m[j], mx[j]);
                float al = exp2f(m[j] - mn);
                m[j] = mn;
                l[j] *= al;
#pragma unroll
                for (int hf = 0; hf < 8; ++hf) oacc[hf][j] *= al;
            }
        }
        float rs[4] = {0.f, 0.f, 0.f, 0.f};
#pragma unroll
        for (int kf = 0; kf < 4; ++kf)
#pragma unroll
            for (int j = 0; j < 4; ++j) {
                float p = exp2f(sf[kf][j] - m[j]);
                rs[j] += p;
                int qq = lgrp * 4 + j;
                int addr = qq * 128 + (((kf * 16 + lrow) * 2) ^ ((qq & 7) << 4));
                *(unsigned short*)(Pl + addr) = f2bf(p);
            }
#pragma unroll
        for (int off = 1; off < 16; off <<= 1)
#pragma unroll
            for (int j = 0; j < 4; ++j) rs[j] += __shfl_xor(rs[j], off);
#pragma unroll
        for (int j = 0; j < 4; ++j) l[j] += rs[j];
        // O += P V
#pragma unroll
        for (int c = 0; c < 2; ++c) {
            int cb = c * 64 + lgrp * 16;
            bf16x8 pf = *(const bf16x8*)(Pl + lrow * 128 + (cb ^ ((lrow & 7) << 4)));
#pragma unroll
            for (int hf = 0; hf < 8; ++hf) {
                int rv = hf * 16 + lrow;
                bf16x8 vf = *(const bf16x8*)(vtb + rv * 128 + (cb ^ ((rv & 7) << 4)));
                oacc[hf] = __builtin_amdgcn_mfma_f32_16x16x32_bf16(pf, vf, oacc[hf], 0, 0, 0);
            }
        }
        __builtin_amdgcn_s_barrier();
        cur ^= 1;
    }
#pragma unroll
    for (int hf = 0; hf < 8; ++hf)
#pragma unroll
        for (int j = 0; j < 4; ++j) {
            float v = oacc[hf][j] / l[j];
            int qg = q0 + lgrp * 4 + j;
            O[(size_t)qg * DD + h * HD + hf * 16 + lrow] = f2bf(v);
        }
}

// ---------------- launch ----------------
extern "C" void kernel_launch(void* const* d_in, const int* in_sizes, int n_in,
                              void* d_out, int out_size, void* d_ws, size_t ws_size,
                              hipStream_t stream)
{
    (void)in_sizes; (void)n_in; (void)out_size; (void)ws_size;
    const int* ids = (const int*)d_in[0];
    // d_in[1] = mask (causal, computed inline)
    const float* fc   = (const float*)d_in[2];
    const float* wemb = (const float*)d_in[3];
    const float* wqkv = (const float*)d_in[4];
    const float* wo   = (const float*)d_in[5];
    const float* w1   = (const float*)d_in[6];
    const float* w3   = (const float*)d_in[7];
    const float* w2   = (const float*)d_in[8];
    const float* anw  = (const float*)d_in[9];
    const float* fnw  = (const float*)d_in[10];
    const float* finw = (const float*)d_in[11];
    const float* wh   = (const float*)d_in[12];
    float* out = (float*)d_out;
    char* ws = (char*)d_ws;

    unsigned short* WQKVT = (unsigned short*)(ws);                 // [L][3072][2048] bf16
    unsigned short* WOT   = (unsigned short*)(ws + 25165824);      // [L][2048][2048]
    unsigned short* W13T  = (unsigned short*)(ws + 41943040);      // [L][11264][2048] (w1/w3 interleaved)
    unsigned short* W2T   = (unsigned short*)(ws + 134217728);     // [L][2048][5632]
    unsigned short* WHT   = (unsigned short*)(ws + 180355072);     // [32000][2048]
    float*          X     = (float*)(ws + 311427072);              // [S][D] fp32
    unsigned short* XN    = (unsigned short*)(ws + 328204288);     // [S][D] bf16
    unsigned short* Qb    = (unsigned short*)(ws + 361758720);     // [NH][S][HD]
    unsigned short* Kb    = (unsigned short*)(ws + 370147328);     // [NKV][S][HD]
    unsigned short* VT    = (unsigned short*)(ws + 372244480);     // [NKV][HD][S]
    unsigned short* AO    = (unsigned short*)(ws + 374341632);     // [S][D] bf16
    unsigned short* G     = (unsigned short*)(ws + 475004928);     // [S][FF] bf16

    // all weight transposes + embedding in ONE dispatch
    prep_all<<<dim3(40064), 256, 0, stream>>>(wqkv, wo, w1, w3, w2, wh, ids, wemb,
                                              WQKVT, WOT, W13T, W2T, WHT, X);

    for (int lyr = 0; lyr < NL; ++lyr) {
        const unsigned short* wqkvT_l = WQKVT + (size_t)lyr * 3072 * 2048;
        const unsigned short* woT_l   = WOT   + (size_t)lyr * 2048 * 2048;
        const unsigned short* w13T_l  = W13T  + (size_t)lyr * 11264 * 2048;
        const unsigned short* w2T_l   = W2T   + (size_t)lyr * 2048 * 5632;

        rmsnorm_bf16<<<dim3(SEQ), 256, 0, stream>>>(X, anw + lyr * DD, XN);
        gemm_bf16<1><<<dim3(24 * 16), 256, 0, stream>>>(XN, wqkvT_l, nullptr, nullptr,
            Qb, Kb, VT, fc, 3072, 2048, 16);
        attn_fwd<<<dim3(512), 256, 0, stream>>>(Qb, Kb, VT, AO);
        gemm_bf16<0><<<dim3(16 * 16), 256, 0, stream>>>(AO, woT_l, X, X,
            nullptr, nullptr, nullptr, nullptr, 2048, 2048, 16);
        rmsnorm_bf16<<<dim3(SEQ), 256, 0, stream>>>(X, fnw + lyr * DD, XN);
        gemm_bf16_128x256<1><<<dim3(44 * 16), 256, 0, stream>>>(XN, w13T_l, G, 11264, 2048, 16);
        gemm_bf16<0><<<dim3(16 * 16), 256, 0, stream>>>(G, w2T_l, X, X,
            nullptr, nullptr, nullptr, nullptr, 2048, 5632, 16);
    }
    rmsnorm_bf16<<<dim3(SEQ), 256, 0, stream>>>(X, finw, XN);
    gemm_bf16_128x256<0><<<dim3(125 * 16), 256, 0, stream>>>(XN, WHT, out, 32000, 2048, 16);
}

// Round 17
// 1143.335 us; speedup vs baseline: 1.0156x; 1.0156x over previous
//
#include <hip/hip_runtime.h>

#define DD 2048
#define SEQ 2048
#define NH 16
#define NKV 4
#define HD 128
#define FFD 5632
#define NL 2

typedef __bf16 bf16x8 __attribute__((ext_vector_type(8)));
typedef float f32x4 __attribute__((ext_vector_type(4)));

#define AS1 __attribute__((address_space(1)))
#define AS3 __attribute__((address_space(3)))

__device__ __forceinline__ unsigned short f2bf(float f) {
    unsigned int u = __builtin_bit_cast(unsigned int, f);
    u += 0x7fffu + ((u >> 16) & 1u);   // round-to-nearest-even
    return (unsigned short)(u >> 16);
}

// ---------------- shared transpose tile body (64x64) ----------------
__device__ __forceinline__ void tc_body(float (*tile)[65],
                                        const float* __restrict__ src,
                                        unsigned short* __restrict__ dst,
                                        int ld_src, int ld_dst, int bx, int by, int nmap)
{
    int c0 = bx * 64, r0 = by * 64;
    int tx = threadIdx.x & 15, ty = threadIdx.x >> 4;
#pragma unroll
    for (int i = 0; i < 4; ++i) {
        int r = ty + i * 16;
        float4 v = *(const float4*)(src + (size_t)(r0 + r) * ld_src + c0 + tx * 4);
        tile[r][tx * 4 + 0] = v.x; tile[r][tx * 4 + 1] = v.y;
        tile[r][tx * 4 + 2] = v.z; tile[r][tx * 4 + 3] = v.w;
    }
    __syncthreads();
#pragma unroll
    for (int i = 0; i < 4; ++i) {
        int c = ty + i * 16;
        int cc = c0 + c;
        int dr = cc;
        if (nmap == 1) dr = ((cc >> 4) << 5) | (cc & 15);
        else if (nmap == 2) dr = (((cc >> 4) << 5) | (cc & 15)) + 16;
        ushort4 o;
        o.x = f2bf(tile[tx * 4 + 0][c]); o.y = f2bf(tile[tx * 4 + 1][c]);
        o.z = f2bf(tile[tx * 4 + 2][c]); o.w = f2bf(tile[tx * 4 + 3][c]);
        *(ushort4*)(dst + (size_t)dr * ld_dst + r0 + tx * 4) = o;
    }
}

// ---------------- fused prep: all weight transposes + embedding gather ----------
__global__ __launch_bounds__(256)
void prep_all(const float* __restrict__ wqkv, const float* __restrict__ wo,
              const float* __restrict__ w1, const float* __restrict__ w3,
              const float* __restrict__ w2, const float* __restrict__ wh,
              const int* __restrict__ ids, const float* __restrict__ wemb,
              unsigned short* __restrict__ WQKVT, unsigned short* __restrict__ WOT,
              unsigned short* __restrict__ W13T, unsigned short* __restrict__ W2T,
              unsigned short* __restrict__ WHT, float* __restrict__ X)
{
    __shared__ float tile[64][65];
    int bid = (int)blockIdx.x;
    if (bid < 16000) {
        tc_body(tile, wh, WHT, 32000, 2048, bid % 500, bid / 500, 0);
    } else if (bid < 21632) {
        int local = bid - 16000;
        int z = local / 2816, r = local % 2816;
        tc_body(tile, w1 + (size_t)z * 2048 * 5632, W13T + (size_t)z * 11264 * 2048,
                5632, 2048, r % 88, r / 88, 1);
    } else if (bid < 27264) {
        int local = bid - 21632;
        int z = local / 2816, r = local % 2816;
        tc_body(tile, w3 + (size_t)z * 2048 * 5632, W13T + (size_t)z * 11264 * 2048,
                5632, 2048, r % 88, r / 88, 2);
    } else if (bid < 32896) {
        int local = bid - 27264;
        int z = local / 2816, r = local % 2816;
        tc_body(tile, w2 + (size_t)z * 5632 * 2048, W2T + (size_t)z * 2048 * 5632,
                2048, 5632, r % 32, r / 32, 0);
    } else if (bid < 35968) {
        int local = bid - 32896;
        int z = local / 1536, r = local % 1536;
        tc_body(tile, wqkv + (size_t)z * 2048 * 3072, WQKVT + (size_t)z * 3072 * 2048,
                3072, 2048, r % 48, r / 48, 0);
    } else if (bid < 38016) {
        int local = bid - 35968;
        int z = local / 1024, r = local % 1024;
        tc_body(tile, wo + (size_t)z * 2048 * 2048, WOT + (size_t)z * 2048 * 2048,
                2048, 2048, r % 32, r / 32, 0);
    } else {
        int s = bid - 38016;
        int id = ids[s];
        const float4* src = (const float4*)(wemb + (size_t)id * DD);
        float4* dst = (float4*)(X + (size_t)s * DD);
        dst[threadIdx.x] = src[threadIdx.x];
        dst[threadIdx.x + 256] = src[threadIdx.x + 256];
    }
}

// ---------------- fused RMSNorm -> bf16 ----------------
__global__ __launch_bounds__(256)
void rmsnorm_bf16(const float* __restrict__ x, const float* __restrict__ w,
                  unsigned short* __restrict__ out)
{
    int row = blockIdx.x;
    int t = threadIdx.x;
    const float4* xr = (const float4*)(x + (size_t)row * DD);
    float4 v0 = xr[t], v1 = xr[t + 256];
    float ss = v0.x * v0.x + v0.y * v0.y + v0.z * v0.z + v0.w * v0.w
             + v1.x * v1.x + v1.y * v1.y + v1.z * v1.z + v1.w * v1.w;
#pragma unroll
    for (int off = 32; off; off >>= 1) ss += __shfl_down(ss, off);
    __shared__ float red[4];
    if ((t & 63) == 0) red[t >> 6] = ss;
    __syncthreads();
    float sc = rsqrtf((red[0] + red[1] + red[2] + red[3]) * (1.0f / DD) + 1e-5f);
    const float4* wr = (const float4*)w;
    float4 w0 = wr[t], w1v = wr[t + 256];
    ushort4 o0, o1;
    o0.x = f2bf(v0.x * sc * w0.x);  o0.y = f2bf(v0.y * sc * w0.y);
    o0.z = f2bf(v0.z * sc * w0.z);  o0.w = f2bf(v0.w * sc * w0.w);
    o1.x = f2bf(v1.x * sc * w1v.x); o1.y = f2bf(v1.y * sc * w1v.y);
    o1.z = f2bf(v1.z * sc * w1v.z); o1.w = f2bf(v1.w * sc * w1v.w);
    ushort4* op = (ushort4*)(out + (size_t)row * DD);
    op[t] = o0;
    op[t + 256] = o1;
}

// ---------------- bf16 MFMA GEMM (128x128 tile, 2-phase counted-vmcnt) ----------
// MODE 0: C[M,N] fp32 (+ optional residual).
// MODE 1: QKV epilogue — RoPE(q,k) head-major bf16 to Qb/Kb; V transposed to VT.
template<int MODE>
__global__ __launch_bounds__(256)
void gemm_bf16(const unsigned short* __restrict__ A, const unsigned short* __restrict__ B,
               float* __restrict__ C, const float* __restrict__ Res,
               unsigned short* __restrict__ Qb, unsigned short* __restrict__ Kb,
               unsigned short* __restrict__ VTp, const float* __restrict__ fcp,
               int N, int K, int mT)
{
    __shared__ __attribute__((aligned(16))) unsigned char smem[65536];
    const int tid = threadIdx.x;
    const int lane = tid & 63;
    const int w = tid >> 6;
    const int nwg = gridDim.x;          // multiple of 8 (launcher guarantees)
    const int qq = nwg >> 3;
    const int logical = ((int)blockIdx.x & 7) * qq + ((int)blockIdx.x >> 3);
    const int m0 = (logical % mT) * 128;
    const int n0 = (logical / mT) * 128;
    const int wm = (w >> 1) * 64, wn = (w & 1) * 64;
    const int lrow = lane & 15, lgrp = lane >> 4;
    const int NT = K >> 6;

    f32x4 acc[4][4];
#pragma unroll
    for (int i = 0; i < 4; ++i)
#pragma unroll
        for (int j = 0; j < 4; ++j) acc[i][j] = 0.f;

    auto stage = [&](int bsel, int kt) {
#pragma unroll
        for (int it = 0; it < 4; ++it) {
            int o = it * 4096 + tid * 16;              // linear LDS byte offset
            int row = o >> 7;
            int col = (o & 127) ^ ((row & 7) << 4);    // pre-swizzled source column
            const char* ga = (const char*)A + ((size_t)(m0 + row) * K + kt) * 2 + col;
            const char* gb = (const char*)B + ((size_t)(n0 + row) * K + kt) * 2 + col;
            __builtin_amdgcn_global_load_lds(
                (AS1 const void*)ga,
                (AS3 void*)(smem + bsel * 32768 + it * 4096 + w * 1024),
                16, 0, 0);
            __builtin_amdgcn_global_load_lds(
                (AS1 const void*)gb,
                (AS3 void*)(smem + bsel * 32768 + 16384 + it * 4096 + w * 1024),
                16, 0, 0);
        }
    };

    stage(0, 0);
    int cur = 0;
    for (int t = 0; t < NT; ++t) {
        if (t + 1 < NT) {
            stage(cur ^ 1, (t + 1) << 6);
            asm volatile("s_waitcnt vmcnt(8)" ::: "memory");   // tile t landed; t+1 in flight
        } else {
            asm volatile("s_waitcnt vmcnt(0)" ::: "memory");   // last tile: nothing newer
        }
        __builtin_amdgcn_s_barrier();
        __builtin_amdgcn_sched_barrier(0);
        const unsigned char* buf = smem + cur * 32768;
#pragma unroll
        for (int kk = 0; kk < 2; ++kk) {
            bf16x8 af[4], bfr[4];
            int cb = kk * 64 + lgrp * 16;
#pragma unroll
            for (int i = 0; i < 4; ++i) {
                int ra = wm + i * 16 + lrow;
                af[i] = *(const bf16x8*)(buf + ra * 128 + (cb ^ ((ra & 7) << 4)));
                int rb = wn + i * 16 + lrow;
                bfr[i] = *(const bf16x8*)(buf + 16384 + rb * 128 + (cb ^ ((rb & 7) << 4)));
            }
#pragma unroll
            for (int i = 0; i < 4; ++i)
#pragma unroll
                for (int j = 0; j < 4; ++j)
                    acc[i][j] = __builtin_amdgcn_mfma_f32_16x16x32_bf16(af[i], bfr[j], acc[i][j], 0, 0, 0);
        }
        __builtin_amdgcn_s_barrier();
        cur ^= 1;
    }

    if constexpr (MODE == 0) {
        const bool hasRes = (Res != nullptr);
#pragma unroll
        for (int i = 0; i < 4; ++i)
#pragma unroll
            for (int j = 0; j < 4; ++j) {
                int r = m0 + wm + i * 16 + lgrp * 4;
                int c = n0 + wn + j * 16 + lrow;
#pragma unroll
                for (int jj = 0; jj < 4; ++jj) {
                    size_t idx = (size_t)(r + jj) * N + c;
                    float v = acc[i][j][jj];
                    if (hasRes) v += Res[idx];
                    C[idx] = v;
                }
            }
    } else {
        // QKV fused epilogue: cols [0,2048) Q-rope, [2048,2560) K-rope, [2560,3072) V->VT
        const float QSCL = 0.12751741530217758f;  // (1/sqrt(128)) * log2(e)
#pragma unroll
        for (int i = 0; i < 4; ++i)
#pragma unroll
            for (int j = 0; j < 4; ++j) {
                int r = m0 + wm + i * 16 + lgrp * 4;
                int cu = n0 + wn + j * 16;          // wave-uniform
                int d = (cu & 127) + lrow;          // 0..127
                if (cu < 2560) {
                    unsigned short* dst;
                    float scl;
                    if (cu < 2048) { dst = Qb + (size_t)(cu >> 7) * SEQ * HD; scl = QSCL; }
                    else           { dst = Kb + (size_t)((cu - 2048) >> 7) * SEQ * HD; scl = 1.f; }
                    int ip = d >> 1;
                    float sgn = (d & 1) ? 1.f : -1.f;
#pragma unroll
                    for (int jj = 0; jj < 4; ++jj) {
                        int s = r + jj;
                        float own = acc[i][j][jj];
                        float par = __shfl_xor(own, 1);
                        float2 cs = *(const float2*)(fcp + ((size_t)s * 64 + ip) * 2);
                        float o = (own * cs.x + sgn * par * cs.y) * scl;
                        dst[(size_t)s * HD + d] = f2bf(o);
                    }
                } else {
                    int kvh = (cu - 2560) >> 7;
                    ushort4 o4;
                    o4.x = f2bf(acc[i][j][0]); o4.y = f2bf(acc[i][j][1]);
                    o4.z = f2bf(acc[i][j][2]); o4.w = f2bf(acc[i][j][3]);
                    *(ushort4*)(VTp + (size_t)(kvh * 128 + d) * SEQ + r) = o4;
                }
            }
    }
}

// ---------------- bf16 MFMA GEMM: 256x256 tile, 8 waves, BK=32 ring, READ-AHEAD ----
// (R7 structure — best measured) FUSE=0: fp32 C. FUSE=1: W13 silu epilogue -> bf16 G.
template<int FUSE>
__global__ __launch_bounds__(512, 1)
void gemm_bf16_256(const unsigned short* __restrict__ A, const unsigned short* __restrict__ B,
                   void* __restrict__ Cout, int N, int K, int mT)
{
    __shared__ __attribute__((aligned(16))) unsigned char smem[131072];
    const int tid = threadIdx.x;
    const int lane = tid & 63;
    const int w = tid >> 6;
    const int nwg = gridDim.x;          // multiple of 8
    const int qq = nwg >> 3;
    const int logical = ((int)blockIdx.x & 7) * qq + ((int)blockIdx.x >> 3);
    const int m0 = (logical % mT) * 256;
    const int n0 = (logical / mT) * 256;
    const int wm2 = (w >> 2) * 128;     // wave M offset (0/128)
    const int lrow = lane & 15, lgrp = (lane >> 4) & 3;
    const int NT = K >> 5;              // BK=32 tiles (NT even, >= 6)

    f32x4 acc[8][4];
#pragma unroll
    for (int i = 0; i < 8; ++i)
#pragma unroll
        for (int j = 0; j < 4; ++j) acc[i][j] = 0.f;

    const int X = (((lrow & 1) << 6) | (lgrp << 4)) ^ ((lrow >> 1) << 4);
    const int aoff = ((wm2 >> 1) + (lrow >> 1)) * 128 + X;                 // + mi*1024
    const int boff = 16384 + (((w & 3) * 32) + (lrow >> 1)) * 128 + X;     // + nj*1024

    auto stage_part = [&](int ktile, int part) {
        const unsigned short* base = part ? B : A;
        const int r0 = part ? n0 : m0;
        const int ktb = ktile << 6;         // byte offset along K (32 elems * 2B)
#pragma unroll
        for (int j = 0; j < 2; ++j) {
            int o = j * 8192 + tid * 16;    // linear dest offset within 16K region
            int p = o >> 7;                 // row-pair 0..127
            int sl = (o & 127) ^ ((p & 7) << 4);   // pre-swizzled source position
            int r = 2 * p + (sl >> 6);
            int cb = sl & 63;
            const char* g = (const char*)base + (size_t)(r0 + r) * K * 2 + ktb + cb;
            __builtin_amdgcn_global_load_lds(
                (AS1 const void*)g,
                (AS3 void*)(smem + (ktile & 3) * 32768 + part * 16384 + o),
                16, 0, 0);
        }
    };

    bf16x8 bE[4], aE[4], bO[4], aO[4], a47[4];

    auto read_ba = [&](int t, bf16x8* bs, bf16x8* as) {
        const unsigned char* buf = smem + (t & 3) * 32768;
#pragma unroll
        for (int nj = 0; nj < 4; ++nj) bs[nj] = *(const bf16x8*)(buf + boff + nj * 1024);
#pragma unroll
        for (int mi = 0; mi < 4; ++mi) as[mi] = *(const bf16x8*)(buf + aoff + mi * 1024);
    };

    auto tile = [&](int t, bf16x8* bc, bf16x8* ac, bf16x8* bn, bf16x8* an) {
        const unsigned char* buf = smem + (t & 3) * 32768;
        if (t + 3 < NT) stage_part(t + 3, 0);
#pragma unroll
        for (int mi = 0; mi < 4; ++mi) a47[mi] = *(const bf16x8*)(buf + aoff + (mi + 4) * 1024);
        asm volatile("s_waitcnt lgkmcnt(4)" ::: "memory");
        __builtin_amdgcn_sched_barrier(0);
        __builtin_amdgcn_s_setprio(1);
#pragma unroll
        for (int mi = 0; mi < 4; ++mi)
#pragma unroll
            for (int nj = 0; nj < 4; ++nj)
                acc[mi][nj] = __builtin_amdgcn_mfma_f32_16x16x32_bf16(ac[mi], bc[nj], acc[mi][nj], 0, 0, 0);
        __builtin_amdgcn_s_setprio(0);
        if (t + 3 < NT) stage_part(t + 3, 1);
        if (t + 1 < NT) {
            if (t + 3 < NT)      { asm volatile("s_waitcnt vmcnt(8)" ::: "memory"); }
            else if (t + 2 < NT) { asm volatile("s_waitcnt vmcnt(4)" ::: "memory"); }
            else                 { asm volatile("s_waitcnt vmcnt(0)" ::: "memory"); }
            __builtin_amdgcn_s_barrier();
            __builtin_amdgcn_sched_barrier(0);
            read_ba(t + 1, bn, an);
            asm volatile("s_waitcnt lgkmcnt(8)" ::: "memory");
        } else {
            asm volatile("s_waitcnt lgkmcnt(0)" ::: "memory");
        }
        __builtin_amdgcn_sched_barrier(0);
        __builtin_amdgcn_s_setprio(1);
#pragma unroll
        for (int mi = 0; mi < 4; ++mi)
#pragma unroll
            for (int nj = 0; nj < 4; ++nj)
                acc[mi + 4][nj] = __builtin_amdgcn_mfma_f32_16x16x32_bf16(a47[mi], bc[nj], acc[mi + 4][nj], 0, 0, 0);
        __builtin_amdgcn_s_setprio(0);
    };

#pragma unroll
    for (int p0 = 0; p0 < 3; ++p0) { stage_part(p0, 0); stage_part(p0, 1); }
    asm volatile("s_waitcnt vmcnt(8)" ::: "memory");
    __builtin_amdgcn_s_barrier();
    __builtin_amdgcn_sched_barrier(0);
    read_ba(0, bE, aE);

    for (int tt = 0; tt < NT; tt += 2) {
        tile(tt, bE, aE, bO, aO);
        tile(tt + 1, bO, aO, bE, aE);
    }

    if constexpr (FUSE == 0) {
        float* C = (float*)Cout;
#pragma unroll
        for (int mi = 0; mi < 8; ++mi)
#pragma unroll
            for (int nj = 0; nj < 4; ++nj) {
                int r = m0 + wm2 + mi * 16 + lgrp * 4;
                int c = n0 + (w & 3) * 64 + nj * 16 + lrow;
#pragma unroll
                for (int jj = 0; jj < 4; ++jj)
                    C[(size_t)(r + jj) * N + c] = acc[mi][nj][jj];
            }
    } else {
        unsigned short* G = (unsigned short*)Cout;
        const int nbase = n0 + (w & 3) * 64;
#pragma unroll
        for (int mi = 0; mi < 8; ++mi)
#pragma unroll
            for (int p = 0; p < 2; ++p) {
                int r = m0 + wm2 + mi * 16 + lgrp * 4;
                int cc = (nbase >> 1) + p * 16 + lrow;
#pragma unroll
                for (int jj = 0; jj < 4; ++jj) {
                    float h1 = acc[mi][2 * p][jj];
                    float h3 = acc[mi][2 * p + 1][jj];
                    float g = h1 / (1.f + __expf(-h1)) * h3;
                    G[(size_t)(r + jj) * FFD + cc] = f2bf(g);
                }
            }
    }
}

// ---------------- flash attention (causal, GQA, exp2-domain, defer-max) ----------
__global__ __launch_bounds__(256)
void attn_fwd(const unsigned short* __restrict__ Qb, const unsigned short* __restrict__ Kb,
              const unsigned short* __restrict__ VTb, unsigned short* __restrict__ O)
{
    __shared__ __attribute__((aligned(16))) unsigned char smem[73728];
    const int bid = (int)blockIdx.x;       // 0..511
    const int j0 = bid & 255;
    const int h = j0 & 15;
    const int qbase = j0 >> 4;             // 0..15
    const int qb = (bid >> 8) ? (31 - qbase) : qbase;
    const int kvh = h >> 2;
    const int tid = threadIdx.x, lane = tid & 63, w = tid >> 6;
    const int lrow = lane & 15, lgrp = lane >> 4;
    const int q0 = qb * 64 + w * 16;
    const float NEG = -1.0e30f;

    bf16x8 qf[4];
    const unsigned short* qrow = Qb + ((size_t)h * SEQ + q0 + lrow) * HD;
#pragma unroll
    for (int c = 0; c < 4; ++c)
        qf[c] = *(const bf16x8*)(qrow + c * 32 + lgrp * 8);

    float m[4], l[4];
    f32x4 oacc[8];
#pragma unroll
    for (int j = 0; j < 8; ++j) oacc[j] = 0.f;
#pragma unroll
    for (int j = 0; j < 4; ++j) { m[j] = NEG; l[j] = 0.f; }

    const char* kbase = (const char*)(Kb + (size_t)kvh * SEQ * HD);
    const char* vbase = (const char*)(VTb + (size_t)kvh * HD * SEQ);
    unsigned char* Pl = smem + 65536 + w * 2048;

    auto stage_kv = [&](int bsel, int t) {
#pragma unroll
        for (int it = 0; it < 4; ++it) {           // K: 16 KB
            int o = it * 4096 + tid * 16;
            int row = o >> 8, col = o & 255;       // 256B rows
            int scol = col ^ ((row & 7) << 4);
            const char* g = kbase + (size_t)(t * 64 + row) * 256 + scol;
            __builtin_amdgcn_global_load_lds(
                (AS1 const void*)g,
                (AS3 void*)(smem + bsel * 32768 + it * 4096 + w * 1024),
                16, 0, 0);
        }
#pragma unroll
        for (int it = 0; it < 4; ++it) {           // VT: 16 KB
            int o = it * 4096 + tid * 16;
            int row = o >> 7, col = o & 127;       // 128B rows
            int scol = col ^ ((row & 7) << 4);
            const char* g = vbase + (size_t)row * (SEQ * 2) + (size_t)t * 128 + scol;
            __builtin_amdgcn_global_load_lds(
                (AS1 const void*)g,
                (AS3 void*)(smem + bsel * 32768 + 16384 + it * 4096 + w * 1024),
                16, 0, 0);
        }
    };

    stage_kv(0, 0);
    int cur = 0;
    for (int t = 0; t <= qb; ++t) {
        if (t < qb) {
            stage_kv(cur ^ 1, t + 1);
            asm volatile("s_waitcnt vmcnt(8)" ::: "memory");   // tile t resident
        } else {
            asm volatile("s_waitcnt vmcnt(0)" ::: "memory");
        }
        __builtin_amdgcn_s_barrier();
        __builtin_amdgcn_sched_barrier(0);
        const unsigned char* kb = smem + cur * 32768;
        const unsigned char* vtb = kb + 16384;

        // S = Q K^T (already in log2 domain via pre-scaled Q)
        f32x4 sf[4];
#pragma unroll
        for (int kf = 0; kf < 4; ++kf) sf[kf] = 0.f;
#pragma unroll
        for (int kf = 0; kf < 4; ++kf) {
            int rb = kf * 16 + lrow;
            int rbase = rb * 256;
            int sw = (rb & 7) << 4;
#pragma unroll
            for (int c = 0; c < 4; ++c) {
                bf16x8 kfr = *(const bf16x8*)(kb + rbase + ((c * 64 + lgrp * 16) ^ sw));
                sf[kf] = __builtin_amdgcn_mfma_f32_16x16x32_bf16(qf[c], kfr, sf[kf], 0, 0, 0);
            }
        }
        const bool diag = (t == qb);
        float mx[4] = {NEG, NEG, NEG, NEG};
#pragma unroll
        for (int kf = 0; kf < 4; ++kf)
#pragma unroll
            for (int j = 0; j < 4; ++j) {
                float v = sf[kf][j];
                if (diag && (t * 64 + kf * 16 + lrow) > (q0 + lgrp * 4 + j)) v = NEG;
                sf[kf][j] = v;
                mx[j] = fmaxf(mx[j], v);
            }
#pragma unroll
        for (int off = 1; off < 16; off <<= 1)
#pragma unroll
            for (int j = 0; j < 4; ++j) mx[j] = fmaxf(mx[j], __shfl_xor(mx[j], off));
        bool need = (mx[0] > m[0] + 8.f) || (mx[1] > m[1] + 8.f) ||
                    (mx[2] > m[2] + 8.f) || (mx[3] > m[3] + 8.f);
        if (__any(need)) {
#pragma unroll
            for (int j = 0; j < 4; ++j) {
                float mn = fmaxf(m[j], mx[j]);
                float al = exp2f(m[j] - mn);
                m[j] = mn;
                l[j] *= al;
#pragma unroll
                for (int hf = 0; hf < 8; ++hf) oacc[hf][j] *= al;
            }
        }
        float rs[4] = {0.f, 0.f, 0.f, 0.f};
#pragma unroll
        for (int kf = 0; kf < 4; ++kf)
#pragma unroll
            for (int j = 0; j < 4; ++j) {
                float p = exp2f(sf[kf][j] - m[j]);
                rs[j] += p;
                int qq = lgrp * 4 + j;
                int addr = qq * 128 + (((kf * 16 + lrow) * 2) ^ ((qq & 7) << 4));
                *(unsigned short*)(Pl + addr) = f2bf(p);
            }
#pragma unroll
        for (int off = 1; off < 16; off <<= 1)
#pragma unroll
            for (int j = 0; j < 4; ++j) rs[j] += __shfl_xor(rs[j], off);
#pragma unroll
        for (int j = 0; j < 4; ++j) l[j] += rs[j];
        // O += P V
#pragma unroll
        for (int c = 0; c < 2; ++c) {
            int cb = c * 64 + lgrp * 16;
            bf16x8 pf = *(const bf16x8*)(Pl + lrow * 128 + (cb ^ ((lrow & 7) << 4)));
#pragma unroll
            for (int hf = 0; hf < 8; ++hf) {
                int rv = hf * 16 + lrow;
                bf16x8 vf = *(const bf16x8*)(vtb + rv * 128 + (cb ^ ((rv & 7) << 4)));
                oacc[hf] = __builtin_amdgcn_mfma_f32_16x16x32_bf16(pf, vf, oacc[hf], 0, 0, 0);
            }
        }
        __builtin_amdgcn_s_barrier();
        cur ^= 1;
    }
#pragma unroll
    for (int hf = 0; hf < 8; ++hf)
#pragma unroll
        for (int j = 0; j < 4; ++j) {
            float v = oacc[hf][j] / l[j];
            int qg = q0 + lgrp * 4 + j;
            O[(size_t)qg * DD + h * HD + hf * 16 + lrow] = f2bf(v);
        }
}

// ---------------- launch ----------------
extern "C" void kernel_launch(void* const* d_in, const int* in_sizes, int n_in,
                              void* d_out, int out_size, void* d_ws, size_t ws_size,
                              hipStream_t stream)
{
    (void)in_sizes; (void)n_in; (void)out_size; (void)ws_size;
    const int* ids = (const int*)d_in[0];
    // d_in[1] = mask (causal, computed inline)
    const float* fc   = (const float*)d_in[2];
    const float* wemb = (const float*)d_in[3];
    const float* wqkv = (const float*)d_in[4];
    const float* wo   = (const float*)d_in[5];
    const float* w1   = (const float*)d_in[6];
    const float* w3   = (const float*)d_in[7];
    const float* w2   = (const float*)d_in[8];
    const float* anw  = (const float*)d_in[9];
    const float* fnw  = (const float*)d_in[10];
    const float* finw = (const float*)d_in[11];
    const float* wh   = (const float*)d_in[12];
    float* out = (float*)d_out;
    char* ws = (char*)d_ws;

    unsigned short* WQKVT = (unsigned short*)(ws);                 // [L][3072][2048] bf16
    unsigned short* WOT   = (unsigned short*)(ws + 25165824);      // [L][2048][2048]
    unsigned short* W13T  = (unsigned short*)(ws + 41943040);      // [L][11264][2048] (w1/w3 interleaved)
    unsigned short* W2T   = (unsigned short*)(ws + 134217728);     // [L][2048][5632]
    unsigned short* WHT   = (unsigned short*)(ws + 180355072);     // [32000][2048]
    float*          X     = (float*)(ws + 311427072);              // [S][D] fp32
    unsigned short* XN    = (unsigned short*)(ws + 328204288);     // [S][D] bf16
    unsigned short* Qb    = (unsigned short*)(ws + 361758720);     // [NH][S][HD]
    unsigned short* Kb    = (unsigned short*)(ws + 370147328);     // [NKV][S][HD]
    unsigned short* VT    = (unsigned short*)(ws + 372244480);     // [NKV][HD][S]
    unsigned short* AO    = (unsigned short*)(ws + 374341632);     // [S][D] bf16
    unsigned short* G     = (unsigned short*)(ws + 475004928);     // [S][FF] bf16

    // all weight transposes + embedding in ONE dispatch
    prep_all<<<dim3(40064), 256, 0, stream>>>(wqkv, wo, w1, w3, w2, wh, ids, wemb,
                                              WQKVT, WOT, W13T, W2T, WHT, X);

    for (int lyr = 0; lyr < NL; ++lyr) {
        const unsigned short* wqkvT_l = WQKVT + (size_t)lyr * 3072 * 2048;
        const unsigned short* woT_l   = WOT   + (size_t)lyr * 2048 * 2048;
        const unsigned short* w13T_l  = W13T  + (size_t)lyr * 11264 * 2048;
        const unsigned short* w2T_l   = W2T   + (size_t)lyr * 2048 * 5632;

        rmsnorm_bf16<<<dim3(SEQ), 256, 0, stream>>>(X, anw + lyr * DD, XN);
        gemm_bf16<1><<<dim3(24 * 16), 256, 0, stream>>>(XN, wqkvT_l, nullptr, nullptr,
            Qb, Kb, VT, fc, 3072, 2048, 16);
        attn_fwd<<<dim3(512), 256, 0, stream>>>(Qb, Kb, VT, AO);
        gemm_bf16<0><<<dim3(16 * 16), 256, 0, stream>>>(AO, woT_l, X, X,
            nullptr, nullptr, nullptr, nullptr, 2048, 2048, 16);
        rmsnorm_bf16<<<dim3(SEQ), 256, 0, stream>>>(X, fnw + lyr * DD, XN);
        gemm_bf16_256<1><<<dim3(8 * 44), 512, 0, stream>>>(XN, w13T_l, G, 11264, 2048, 8);
        gemm_bf16<0><<<dim3(16 * 16), 256, 0, stream>>>(G, w2T_l, X, X,
            nullptr, nullptr, nullptr, nullptr, 2048, 5632, 16);
    }
    rmsnorm_bf16<<<dim3(SEQ), 256, 0, stream>>>(X, finw, XN);
    gemm_bf16_256<0><<<dim3(8 * 125), 512, 0, stream>>>(XN, WHT, out, 32000, 2048, 8);
}